// Round 15
// baseline (241.644 us; speedup 1.0000x reference)
//
#include <hip/hip_runtime.h>
#include <stdint.h>

#define B_ 2
#define S_ 2048
#define D_ 1024
#define H_ 16
#define HD_ 64
#define NC_ 5120   // QKV GEMM output width

typedef unsigned short ushort_t;
typedef __bf16 bf16x8_t __attribute__((ext_vector_type(8)));
typedef unsigned short us8 __attribute__((ext_vector_type(8)));
typedef float f32x4 __attribute__((ext_vector_type(4)));
typedef unsigned int u32x4 __attribute__((ext_vector_type(4)));

using gq_t = const unsigned int __attribute__((address_space(1)));
using lq_t = unsigned int __attribute__((address_space(3)));

__device__ __forceinline__ unsigned short f2bf(float f) {
    unsigned u = __builtin_bit_cast(unsigned, f);
    u += 0x7fffu + ((u >> 16) & 1u);
    return (unsigned short)(u >> 16);
}
__device__ __forceinline__ float bf2f(unsigned short h) {
    unsigned u = ((unsigned)h) << 16;
    return __builtin_bit_cast(float, u);
}
__device__ __forceinline__ unsigned cvt_pk_bf16(float lo, float hi) {
    unsigned r;
    asm("v_cvt_pk_bf16_f32 %0, %1, %2" : "=v"(r) : "v"(lo), "v"(hi));
    return r;
}
__device__ __forceinline__ f32x4 mfma16(us8 a, us8 b, f32x4 c) {
    return __builtin_amdgcn_mfma_f32_16x16x32_bf16(
        __builtin_bit_cast(bf16x8_t, a), __builtin_bit_cast(bf16x8_t, b), c, 0, 0, 0);
}
__device__ __forceinline__ void gload16(const void* g, void* l) {
    __builtin_amdgcn_global_load_lds((gq_t*)g, (lq_t*)l, 16, 0, 0);
}
// K-row storage bit-permutation: pos bits [kk|jh|g|r] <- kv bits [kk|g|jh|r]
__device__ __forceinline__ int invpi(int p) {
    return (p & 0x20) | ((p & 0x0C) << 1) | ((p & 0x10) >> 2) | (p & 3);
}

// ---------------- convert X f32 -> bf16 ----------------
__global__ __launch_bounds__(256) void k_convert_x(const float* __restrict__ X,
                                                   ushort_t* __restrict__ Xb) {
    int i = (blockIdx.x * 256 + threadIdx.x) * 4;
    float4 v = *reinterpret_cast<const float4*>(X + i);
    ushort4 o;
    o.x = f2bf(v.x); o.y = f2bf(v.y); o.z = f2bf(v.z); o.w = f2bf(v.w);
    *reinterpret_cast<ushort4*>(Xb + i) = o;
}

// ---------------- all weight transposes in one kernel ----------------
__global__ __launch_bounds__(256) void k_transpose_all(const float* __restrict__ Wq,
                                                       const float* __restrict__ Wk,
                                                       const float* __restrict__ Wv,
                                                       const float* __restrict__ Wo,
                                                       ushort_t* __restrict__ Wt,
                                                       ushort_t* __restrict__ Wot) {
    __shared__ float lds[64 * 65];
    int bx = blockIdx.x;
    const float* W; ushort_t* dst; int N, nbase, x;
    if (bx < 32)      { W = Wq; dst = Wt;  N = 2048; nbase = 0;    x = bx; }
    else if (bx < 64) { W = Wk; dst = Wt;  N = 2048; nbase = 2048; x = bx - 32; }
    else if (bx < 80) { W = Wv; dst = Wt;  N = 1024; nbase = 4096; x = bx - 64; }
    else              { W = Wo; dst = Wot; N = 1024; nbase = 0;    x = bx - 80; }
    int n0 = x * 64, k0 = blockIdx.y * 64;
    int t = threadIdx.x;
#pragma unroll
    for (int i = 0; i < 16; i++) {
        int idx = i * 256 + t;
        int r = idx >> 6, c = idx & 63;
        lds[c * 65 + r] = W[(size_t)(k0 + r) * N + (n0 + c)];
    }
    __syncthreads();
#pragma unroll
    for (int i = 0; i < 16; i++) {
        int idx = i * 256 + t;
        int nn = idx >> 6, k = idx & 63;
        dst[(size_t)(nbase + n0 + nn) * 1024 + (k0 + k)] = f2bf(lds[nn * 65 + k]);
    }
}

// ------- 128x128x(K=1024) bf16 MFMA GEMM core, double-buffered prefetch -------
__device__ __forceinline__ void gemm_tile_db(const ushort_t* __restrict__ A,
                                             const ushort_t* __restrict__ Bt,
                                             int m0, int n0,
                                             ushort_t* ldsA, ushort_t* ldsB,  // each 2*8192
                                             f32x4 acc[4][4]) {
    const int K = 1024;
    int t = threadIdx.x;
    int w = t >> 6, l = t & 63;
    int wr = (w >> 1) * 64, wc = (w & 1) * 64;
    int lo16 = l & 15, lg = l >> 4;
#pragma unroll
    for (int m = 0; m < 4; m++)
#pragma unroll
        for (int n = 0; n < 4; n++) acc[m][n] = f32x4{0.f, 0.f, 0.f, 0.f};

    auto stage = [&](int buf, int k0) {
#pragma unroll
        for (int i = 0; i < 4; i++) {
            int c = i * 256 + t;
            int row = c >> 3, co = (c & 7) * 8;
            gload16(A + (size_t)(m0 + row) * K + k0 + co, ldsA + buf * 8192 + c * 8);
            gload16(Bt + (size_t)(n0 + row) * K + k0 + co, ldsB + buf * 8192 + c * 8);
        }
    };

    stage(0, 0);
    __syncthreads();
    int buf = 0;
    for (int k0 = 0; k0 < K; k0 += 64) {
        if (k0 + 64 < K) stage(buf ^ 1, k0 + 64);
        const ushort_t* la = ldsA + buf * 8192;
        const ushort_t* lb = ldsB + buf * 8192;
#pragma unroll
        for (int kk = 0; kk < 2; kk++) {
            us8 af[4], bfr[4];
#pragma unroll
            for (int m = 0; m < 4; m++)
                af[m] = *(const us8*)(la + (wr + m * 16 + lo16) * 64 + kk * 32 + lg * 8);
#pragma unroll
            for (int n = 0; n < 4; n++)
                bfr[n] = *(const us8*)(lb + (wc + n * 16 + lo16) * 64 + kk * 32 + lg * 8);
#pragma unroll
            for (int m = 0; m < 4; m++)
#pragma unroll
                for (int n = 0; n < 4; n++)
                    acc[m][n] = mfma16(af[m], bfr[n], acc[m][n]);
        }
        __syncthreads();
        buf ^= 1;
    }
}

// ---------------- QKV projection GEMM -> plain bf16 C[4096][5120] ----------------
__global__ __launch_bounds__(256) void k_gemm_qkv(const ushort_t* __restrict__ Xb,
                                                  const ushort_t* __restrict__ Wt,
                                                  ushort_t* __restrict__ C) {
    __shared__ __align__(16) ushort_t ldsA[2 * 8192];
    __shared__ __align__(16) ushort_t ldsB[2 * 8192];
    f32x4 acc[4][4];
    int m0 = blockIdx.y * 128, n0 = blockIdx.x * 128;
    gemm_tile_db(Xb, Wt, m0, n0, ldsA, ldsB, acc);
    int t = threadIdx.x, w = t >> 6, l = t & 63;
    int wr = (w >> 1) * 64, wc = (w & 1) * 64, lo16 = l & 15, lg = l >> 4;
#pragma unroll
    for (int m = 0; m < 4; m++)
#pragma unroll
        for (int n = 0; n < 4; n++)
#pragma unroll
            for (int r = 0; r < 4; r++)
                C[(size_t)(m0 + wr + m * 16 + lg * 4 + r) * NC_ + (n0 + wc + n * 16 + lo16)] =
                    f2bf(acc[m][n][r]);
}

// ---------------- output GEMM: Yb @ Wo -> f32 ----------------
__global__ __launch_bounds__(256) void k_gemm_out(const ushort_t* __restrict__ Yb,
                                                  const ushort_t* __restrict__ Wot,
                                                  float* __restrict__ Out) {
    __shared__ __align__(16) ushort_t ldsA[2 * 8192];
    __shared__ __align__(16) ushort_t ldsB[2 * 8192];
    f32x4 acc[4][4];
    int m0 = blockIdx.y * 128, n0 = blockIdx.x * 128;
    gemm_tile_db(Yb, Wot, m0, n0, ldsA, ldsB, acc);
    int t = threadIdx.x, w = t >> 6, l = t & 63;
    int wr = (w >> 1) * 64, wc = (w & 1) * 64, lo16 = l & 15, lg = l >> 4;
#pragma unroll
    for (int m = 0; m < 4; m++)
#pragma unroll
        for (int n = 0; n < 4; n++)
#pragma unroll
            for (int r = 0; r < 4; r++)
                Out[(size_t)(m0 + wr + m * 16 + lg * 4 + r) * 1024 + (n0 + wc + n * 16 + lo16)] =
                    acc[m][n][r];
}

// ---------------- V transpose per head from C: [S][64] -> Vt[64][S] ----------------
__global__ __launch_bounds__(256) void k_transpose_v(const ushort_t* __restrict__ C,
                                                     ushort_t* __restrict__ Vt) {
    __shared__ ushort_t lds[64 * 72];
    int bh = blockIdx.x, s0 = blockIdx.y * 64;
    int b = bh >> 4, h = bh & 15;
    const ushort_t* src = C + (size_t)(b * S_ + s0) * NC_ + 4096 + h * 64;
    ushort_t* dst = Vt + (size_t)bh * HD_ * S_ + s0;
    int t = threadIdx.x;
#pragma unroll
    for (int i = 0; i < 16; i++) {
        int idx = i * 256 + t;
        int s = idx >> 6, d = idx & 63;
        lds[d * 72 + s] = src[(size_t)s * NC_ + d];
    }
    __syncthreads();
#pragma unroll
    for (int i = 0; i < 16; i++) {
        int idx = i * 256 + t;
        int d = idx >> 6, s = idx & 63;
        dst[(size_t)d * S_ + s] = lds[d * 72 + s];
    }
}

// ---------------- fused dual flash attention + memory term + stats ----------------
// R6-verified mapping/algebra; W=28 window; merged two-stream step body.
// This round: V fragments read DIRECT from global Vt (L2-resident, natural-kv
// order proven identical to the staged bytes) -> LDS 49.7->33.3KB -> 4 blocks/CU.
__global__ __launch_bounds__(256, 4) void k_attn(
    const ushort_t* __restrict__ Cg, const ushort_t* __restrict__ Vtg,
    const float* __restrict__ mask,
    const float* __restrict__ lam_q1, const float* __restrict__ lam_q2,
    const float* __restrict__ lam_k1, const float* __restrict__ lam_k2,
    const float* __restrict__ mgate, const float* __restrict__ memp,
    const float* __restrict__ zp, float* __restrict__ Oatt, float* __restrict__ stats) {
    __shared__ __align__(16) ushort_t smem[2 * 8192];   // 2 x (K1 | K2)
    __shared__ __align__(16) float ldsAdj[2][64];
    ushort_t* ldsM = smem;   // epilogue overlay (5120 <= 16384)

    int bx = blockIdx.x;
    int xcd = bx & 7, slot = bx >> 3;
    int sub = slot & 3;
    int qt = 31 - (slot >> 2);
    int h = (sub & 1) ? (15 - xcd) : xcd;
    int b = sub >> 1;
    int bh = b * 16 + h;
    int q0 = qt * 64;
    int t = threadIdx.x, w = t >> 6, l = t & 63;
    int lo16 = l & 15, lg = l >> 4;

    const ushort_t* Cb  = Cg + (size_t)(b * S_) * NC_;
    const ushort_t* Qp  = Cb + h * 128;
    const ushort_t* Kp  = Cb + 2048 + h * 128;
    const ushort_t* Vt  = Vtg + (size_t)bh * HD_ * S_;

    int qrowA = q0 + w * 16 + lo16;
    us8 q1f[2], q2f[2];
    q1f[0] = *(const us8*)(Qp + (size_t)qrowA * NC_ + lg * 8);
    q1f[1] = *(const us8*)(Qp + (size_t)qrowA * NC_ + 32 + lg * 8);
    q2f[0] = *(const us8*)(Qp + (size_t)qrowA * NC_ + 64 + lg * 8);
    q2f[1] = *(const us8*)(Qp + (size_t)qrowA * NC_ + 96 + lg * 8);

    float la = 0.f, lb = 0.f;
    for (int i = 0; i < HD_; i++) { la += lam_q1[i] * lam_k1[i]; lb += lam_q2[i] * lam_k2[i]; }
    float lam = __expf(la) - __expf(lb) + 0.8f;

    const float LOG2E = 1.4426950408889634f;
    float slope2 = exp2f(-0.5f * (float)(h + 1)) * LOG2E;
    const float scale2 = 0.125f * LOG2E;

    int qcol = q0 + w * 16 + lo16;
    float qterm = -slope2 * (float)qcol - 8.0f;

    int koff[4];
#pragma unroll
    for (int n = 0; n < 4; n++) koff[n] = ((n >> 1) << 5) | (lg << 3) | ((n & 1) << 2);

    int fs = (int)floorf(((float)q0 - 63.0f - 28.0f / slope2) * (1.0f / 64.0f));
    if (fs < 0) fs = 0;

    int sx0 = (lg ^ (lo16 & 7)) * 8;
    int sx1 = ((4 + lg) ^ (lo16 & 7)) * 8;

    // per-lane V row base (B-operand: d = n*16+lo16, k-slot = kk*32+lg*8+j natural kv)
    const ushort_t* vrow[4];
#pragma unroll
    for (int n = 0; n < 4; n++) vrow[n] = Vt + (size_t)(n * 16 + lo16) * S_ + lg * 8;

    f32x4 o1[5], o2[5];
#pragma unroll
    for (int n = 0; n < 5; n++) { o1[n] = f32x4{0, 0, 0, 0}; o2[n] = f32x4{0, 0, 0, 0}; }

    const us8 ones8 = {0x3F80, 0x3F80, 0x3F80, 0x3F80, 0x3F80, 0x3F80, 0x3F80, 0x3F80};

    auto stage = [&](int buf, int kv0) {
        ushort_t* base = smem + buf * 8192;
#pragma unroll
        for (int i = 0; i < 2; i++) {
            int c = i * 256 + t, row = c >> 3;
            int co = ((c & 7) ^ (row & 7)) * 8;
            int kvsrc = kv0 + invpi(row);
            const ushort_t* krow = Kp + (size_t)kvsrc * NC_;
            gload16(krow + co, base + c * 8);
            gload16(krow + 64 + co, base + 4096 + c * 8);
        }
        if (t < 64) {
            int kvloc = invpi(t);
            ldsAdj[buf][t] = (1.f - mask[(size_t)b * S_ + kv0 + kvloc]) * -1.4426950e9f +
                             slope2 * (float)(kv0 + kvloc);
        }
    };

    int cur = 0;
    stage(0, qt * 64);
    __syncthreads();
    for (int step = qt; step >= fs; --step) {
        if (step - 1 >= fs) stage(cur ^ 1, (step - 1) * 64);
        int kv0 = step * 64;
        ushort_t* base = smem + cur * 8192;
        const ushort_t* ldsK1 = base;
        const ushort_t* ldsK2 = base + 4096;

        f32x4 madjq[4];
#pragma unroll
        for (int n = 0; n < 4; n++) {
            f32x4 m = *(const f32x4*)(&ldsAdj[cur][n * 16 + lg * 4]);
#pragma unroll
            for (int r = 0; r < 4; r++) m[r] += qterm;
            madjq[n] = m;
        }

        // V fragments direct from global (L2-hit); independent of softmax chain
        us8 vf[2][4];
#pragma unroll
        for (int kk = 0; kk < 2; kk++)
#pragma unroll
            for (int n = 0; n < 4; n++)
                vf[kk][n] = *(const us8*)(vrow[n] + kv0 + kk * 32);

        // --- merged two-stream QK^T (interleaved MFMAs) ---
        f32x4 s1[4], s2[4];
#pragma unroll
        for (int n = 0; n < 4; n++) { s1[n] = f32x4{0, 0, 0, 0}; s2[n] = f32x4{0, 0, 0, 0}; }
#pragma unroll
        for (int kk = 0; kk < 2; kk++) {
            int sxk = kk ? sx1 : sx0;
#pragma unroll
            for (int n = 0; n < 4; n++) {
                us8 kf1 = *(const us8*)(ldsK1 + (n * 16 + lo16) * 64 + sxk);
                us8 kf2 = *(const us8*)(ldsK2 + (n * 16 + lo16) * 64 + sxk);
                s1[n] = mfma16(kf1, q1f[kk], s1[n]);
                s2[n] = mfma16(kf2, q2f[kk], s2[n]);
            }
        }

        // --- merged softmax (frozen max, log2 domain) ---
#pragma unroll
        for (int n = 0; n < 4; n++)
#pragma unroll
            for (int r = 0; r < 4; r++) {
                s1[n][r] = fmaf(s1[n][r], scale2, madjq[n][r]);
                s2[n][r] = fmaf(s2[n][r], scale2, madjq[n][r]);
            }
        if (step == qt) {
#pragma unroll
            for (int n = 0; n < 4; n++) {
                int kvn = kv0 + koff[n];
#pragma unroll
                for (int r = 0; r < 4; r++)
                    if (kvn + r > qcol) { s1[n][r] = -1e30f; s2[n][r] = -1e30f; }
            }
        }
#pragma unroll
        for (int n = 0; n < 4; n++)
#pragma unroll
            for (int r = 0; r < 4; r++) {
                s1[n][r] = __builtin_amdgcn_exp2f(s1[n][r]);
                s2[n][r] = __builtin_amdgcn_exp2f(s2[n][r]);
            }
        us8 pa1[2], pa2[2];
#pragma unroll
        for (int kk = 0; kk < 2; kk++) {
            u32x4 u1, u2;
            u1[0] = cvt_pk_bf16(s1[2 * kk][0], s1[2 * kk][1]);
            u1[1] = cvt_pk_bf16(s1[2 * kk][2], s1[2 * kk][3]);
            u1[2] = cvt_pk_bf16(s1[2 * kk + 1][0], s1[2 * kk + 1][1]);
            u1[3] = cvt_pk_bf16(s1[2 * kk + 1][2], s1[2 * kk + 1][3]);
            u2[0] = cvt_pk_bf16(s2[2 * kk][0], s2[2 * kk][1]);
            u2[1] = cvt_pk_bf16(s2[2 * kk][2], s2[2 * kk][3]);
            u2[2] = cvt_pk_bf16(s2[2 * kk + 1][0], s2[2 * kk + 1][1]);
            u2[3] = cvt_pk_bf16(s2[2 * kk + 1][2], s2[2 * kk + 1][3]);
            pa1[kk] = __builtin_bit_cast(us8, u1);
            pa2[kk] = __builtin_bit_cast(us8, u2);
        }

        // --- merged PV (shared vf) ---
#pragma unroll
        for (int kk = 0; kk < 2; kk++) {
            o1[4] = mfma16(pa1[kk], ones8, o1[4]);
            o2[4] = mfma16(pa2[kk], ones8, o2[4]);
#pragma unroll
            for (int n = 0; n < 4; n++) {
                o1[n] = mfma16(pa1[kk], vf[kk][n], o1[n]);
                o2[n] = mfma16(pa2[kk], vf[kk][n], o2[n]);
            }
        }
        __syncthreads();
        cur ^= 1;
    }

    // ---- epilogue: sigma@mem, sigma@z, gate combine, stats ----
    for (int i = t; i < 80 * 64; i += 256) {
        int n = i >> 6, kd = i & 63;
        float v = 0.f;
        if (n < 64) v = memp[((size_t)h * 64 + kd) * 64 + n];
        else if (n == 64) v = zp[h * 64 + kd];
        ldsM[i] = f2bf(v);
    }
    __syncthreads();

    us8 sf[2];
#pragma unroll
    for (int kk = 0; kk < 2; kk++) {
#pragma unroll
        for (int j = 0; j < 8; j++) {
            float x = bf2f(q1f[kk][j]);
            float e = (x > 0.f) ? x : (__expf(x) - 1.f);
            sf[kk][j] = f2bf(e + 1.f);
        }
    }
    f32x4 mv[5];
#pragma unroll
    for (int n = 0; n < 5; n++) mv[n] = f32x4{0, 0, 0, 0};
#pragma unroll
    for (int kk = 0; kk < 2; kk++)
#pragma unroll
        for (int n = 0; n < 5; n++) {
            us8 mb = *(const us8*)(ldsM + (n * 16 + lo16) * 64 + kk * 32 + lg * 8);
            mv[n] = mfma16(sf[kk], mb, mv[n]);
        }
    float denom[4];
#pragma unroll
    for (int r = 0; r < 4; r++) denom[r] = __shfl(mv[4][r], lg * 16);

    float gsum = 0.f, gsq = 0.f;
#pragma unroll
    for (int n = 0; n < 4; n++) {
        int d = n * 16 + lo16;
        float gate = 1.f / (1.f + __expf(-mgate[h * HD_ + d]));
#pragma unroll
        for (int r = 0; r < 4; r++) {
            int q = q0 + w * 16 + lg * 4 + r;
            float dmv = mv[n][r] / denom[r];
            float oa = o1[n][r] / o1[4][r] - lam * (o2[n][r] / o2[4][r]);
            float val = gate * dmv + (1.f - gate) * oa;
            Oatt[((size_t)bh * S_ + q) * HD_ + d] = val;
            gsum += val;
            gsq += val * val;
        }
    }
#pragma unroll
    for (int off = 1; off < 64; off <<= 1) {
        gsum += __shfl_xor(gsum, off);
        gsq += __shfl_xor(gsq, off);
    }
    if (l == 0) {
        atomicAdd(&stats[bh * 2 + 0], gsum);
        atomicAdd(&stats[bh * 2 + 1], gsq);
    }
}

// ---------------- groupnorm normalize -> Yb bf16 [B][S][D] (x 0.2) ----------------
__global__ __launch_bounds__(256) void k_norm(const float* __restrict__ Oatt,
                                              const float* __restrict__ stats,
                                              const float* __restrict__ gw,
                                              const float* __restrict__ gb,
                                              ushort_t* __restrict__ Yb) {
    int i4 = (blockIdx.x * 256 + threadIdx.x) * 4;
    int bh = i4 >> 17;
    int rest = i4 & 131071;
    int s = rest >> 6, d = rest & 63;
    int b = bh >> 4, h = bh & 15;
    float mu = stats[bh * 2] * (1.f / 131072.f);
    float var = stats[bh * 2 + 1] * (1.f / 131072.f) - mu * mu;
    float rstd = rsqrtf(var + 1e-5f);
    float4 v = *reinterpret_cast<const float4*>(Oatt + i4);
    int c = h * 64 + d;
    ushort4 o;
    o.x = f2bf(((v.x - mu) * rstd * gw[c + 0] + gb[c + 0]) * 0.2f);
    o.y = f2bf(((v.y - mu) * rstd * gw[c + 1] + gb[c + 1]) * 0.2f);
    o.z = f2bf(((v.z - mu) * rstd * gw[c + 2] + gb[c + 2]) * 0.2f);
    o.w = f2bf(((v.w - mu) * rstd * gw[c + 3] + gb[c + 3]) * 0.2f);
    *reinterpret_cast<ushort4*>(Yb + ((size_t)(b * S_ + s)) * 1024 + c) = o;
}

extern "C" void kernel_launch(void* const* d_in, const int* in_sizes, int n_in,
                              void* d_out, int out_size, void* d_ws, size_t ws_size,
                              hipStream_t stream) {
    const float* X      = (const float*)d_in[0];
    const float* mask   = (const float*)d_in[1];
    const float* Wq     = (const float*)d_in[2];
    const float* Wk     = (const float*)d_in[3];
    const float* Wv     = (const float*)d_in[4];
    const float* Wo     = (const float*)d_in[5];
    const float* lam_q1 = (const float*)d_in[6];
    const float* lam_q2 = (const float*)d_in[7];
    const float* lam_k1 = (const float*)d_in[8];
    const float* lam_k2 = (const float*)d_in[9];
    const float* gw     = (const float*)d_in[10];
    const float* gb     = (const float*)d_in[11];
    const float* mgate  = (const float*)d_in[12];
    const float* memp   = (const float*)d_in[13];
    const float* zp     = (const float*)d_in[14];

    char* p = (char*)d_ws;
    auto alloc = [&](size_t bytes) -> char* {
        char* r = p;
        p += (bytes + 255) & ~(size_t)255;
        return r;
    };
    ushort_t* Xb  = (ushort_t*)alloc((size_t)4096 * 1024 * 2);
    ushort_t* Wt  = (ushort_t*)alloc((size_t)5120 * 1024 * 2);
    ushort_t* Wot = (ushort_t*)alloc((size_t)1024 * 1024 * 2);
    ushort_t* C   = (ushort_t*)alloc((size_t)4096 * NC_ * 2);
    ushort_t* Vt  = (ushort_t*)alloc((size_t)B_ * H_ * S_ * HD_ * 2);
    float*    Oat = (float*)alloc((size_t)B_ * H_ * S_ * HD_ * 4);
    ushort_t* Yb  = (ushort_t*)alloc((size_t)4096 * 1024 * 2);
    float*    st  = (float*)alloc(256);

    k_convert_x<<<4096, 256, 0, stream>>>(X, Xb);
    k_transpose_all<<<dim3(96, 16), 256, 0, stream>>>(Wq, Wk, Wv, Wo, Wt, Wot);
    k_gemm_qkv<<<dim3(40, 32), 256, 0, stream>>>(Xb, Wt, C);
    k_transpose_v<<<dim3(32, 32), 256, 0, stream>>>(C, Vt);
    hipMemsetAsync(st, 0, 64 * sizeof(float), stream);
    k_attn<<<1024, 256, 0, stream>>>(C, Vt, mask, lam_q1, lam_q2,
                                     lam_k1, lam_k2, mgate, memp, zp, Oat, st);
    k_norm<<<4096, 256, 0, stream>>>(Oat, st, gw, gb, Yb);
    k_gemm_out<<<dim3(8, 32), 256, 0, stream>>>(Yb, Wot, (float*)d_out);
}

// Round 16
// 180.729 us; speedup vs baseline: 1.3370x; 1.3370x over previous
//
#include <hip/hip_runtime.h>
#include <stdint.h>

#define B_ 2
#define S_ 2048
#define D_ 1024
#define H_ 16
#define HD_ 64
#define NC_ 5120   // QKV GEMM output width

typedef unsigned short ushort_t;
typedef __bf16 bf16x8_t __attribute__((ext_vector_type(8)));
typedef unsigned short us8 __attribute__((ext_vector_type(8)));
typedef float f32x4 __attribute__((ext_vector_type(4)));
typedef unsigned int u32x4 __attribute__((ext_vector_type(4)));

using gq_t = const unsigned int __attribute__((address_space(1)));
using lq_t = unsigned int __attribute__((address_space(3)));

__device__ __forceinline__ unsigned short f2bf(float f) {
    unsigned u = __builtin_bit_cast(unsigned, f);
    u += 0x7fffu + ((u >> 16) & 1u);
    return (unsigned short)(u >> 16);
}
__device__ __forceinline__ float bf2f(unsigned short h) {
    unsigned u = ((unsigned)h) << 16;
    return __builtin_bit_cast(float, u);
}
__device__ __forceinline__ unsigned cvt_pk_bf16(float lo, float hi) {
    unsigned r;
    asm("v_cvt_pk_bf16_f32 %0, %1, %2" : "=v"(r) : "v"(lo), "v"(hi));
    return r;
}
__device__ __forceinline__ f32x4 mfma16(us8 a, us8 b, f32x4 c) {
    return __builtin_amdgcn_mfma_f32_16x16x32_bf16(
        __builtin_bit_cast(bf16x8_t, a), __builtin_bit_cast(bf16x8_t, b), c, 0, 0, 0);
}
__device__ __forceinline__ void gload16(const void* g, void* l) {
    __builtin_amdgcn_global_load_lds((gq_t*)g, (lq_t*)l, 16, 0, 0);
}
// K-row storage bit-permutation: pos bits [kk|jh|g|r] <- kv bits [kk|g|jh|r]
__device__ __forceinline__ int invpi(int p) {
    return (p & 0x20) | ((p & 0x0C) << 1) | ((p & 0x10) >> 2) | (p & 3);
}

// ---------------- convert X f32 -> bf16 ----------------
__global__ __launch_bounds__(256) void k_convert_x(const float* __restrict__ X,
                                                   ushort_t* __restrict__ Xb) {
    int i = (blockIdx.x * 256 + threadIdx.x) * 4;
    float4 v = *reinterpret_cast<const float4*>(X + i);
    ushort4 o;
    o.x = f2bf(v.x); o.y = f2bf(v.y); o.z = f2bf(v.z); o.w = f2bf(v.w);
    *reinterpret_cast<ushort4*>(Xb + i) = o;
}

// ---------------- all weight transposes in one kernel ----------------
__global__ __launch_bounds__(256) void k_transpose_all(const float* __restrict__ Wq,
                                                       const float* __restrict__ Wk,
                                                       const float* __restrict__ Wv,
                                                       const float* __restrict__ Wo,
                                                       ushort_t* __restrict__ Wt,
                                                       ushort_t* __restrict__ Wot) {
    __shared__ float lds[64 * 65];
    int bx = blockIdx.x;
    const float* W; ushort_t* dst; int N, nbase, x;
    if (bx < 32)      { W = Wq; dst = Wt;  N = 2048; nbase = 0;    x = bx; }
    else if (bx < 64) { W = Wk; dst = Wt;  N = 2048; nbase = 2048; x = bx - 32; }
    else if (bx < 80) { W = Wv; dst = Wt;  N = 1024; nbase = 4096; x = bx - 64; }
    else              { W = Wo; dst = Wot; N = 1024; nbase = 0;    x = bx - 80; }
    int n0 = x * 64, k0 = blockIdx.y * 64;
    int t = threadIdx.x;
#pragma unroll
    for (int i = 0; i < 16; i++) {
        int idx = i * 256 + t;
        int r = idx >> 6, c = idx & 63;
        lds[c * 65 + r] = W[(size_t)(k0 + r) * N + (n0 + c)];
    }
    __syncthreads();
#pragma unroll
    for (int i = 0; i < 16; i++) {
        int idx = i * 256 + t;
        int nn = idx >> 6, k = idx & 63;
        dst[(size_t)(nbase + n0 + nn) * 1024 + (k0 + k)] = f2bf(lds[nn * 65 + k]);
    }
}

// ------- 128x128x(K=1024) bf16 MFMA GEMM core, double-buffered prefetch -------
// stage(next) issued BEFORE compute(cur); single barrier per K-step serves both
// "next buffer loaded" (vmcnt drain at barrier) and "cur safe to overwrite".
__device__ __forceinline__ void gemm_tile_db(const ushort_t* __restrict__ A,
                                             const ushort_t* __restrict__ Bt,
                                             int m0, int n0,
                                             ushort_t* ldsA, ushort_t* ldsB,  // each 2*8192
                                             f32x4 acc[4][4]) {
    const int K = 1024;
    int t = threadIdx.x;
    int w = t >> 6, l = t & 63;
    int wr = (w >> 1) * 64, wc = (w & 1) * 64;
    int lo16 = l & 15, lg = l >> 4;
#pragma unroll
    for (int m = 0; m < 4; m++)
#pragma unroll
        for (int n = 0; n < 4; n++) acc[m][n] = f32x4{0.f, 0.f, 0.f, 0.f};

    auto stage = [&](int buf, int k0) {
#pragma unroll
        for (int i = 0; i < 4; i++) {
            int c = i * 256 + t;
            int row = c >> 3, co = (c & 7) * 8;
            gload16(A + (size_t)(m0 + row) * K + k0 + co, ldsA + buf * 8192 + c * 8);
            gload16(Bt + (size_t)(n0 + row) * K + k0 + co, ldsB + buf * 8192 + c * 8);
        }
    };

    stage(0, 0);
    __syncthreads();
    int buf = 0;
    for (int k0 = 0; k0 < K; k0 += 64) {
        if (k0 + 64 < K) stage(buf ^ 1, k0 + 64);
        const ushort_t* la = ldsA + buf * 8192;
        const ushort_t* lb = ldsB + buf * 8192;
#pragma unroll
        for (int kk = 0; kk < 2; kk++) {
            us8 af[4], bfr[4];
#pragma unroll
            for (int m = 0; m < 4; m++)
                af[m] = *(const us8*)(la + (wr + m * 16 + lo16) * 64 + kk * 32 + lg * 8);
#pragma unroll
            for (int n = 0; n < 4; n++)
                bfr[n] = *(const us8*)(lb + (wc + n * 16 + lo16) * 64 + kk * 32 + lg * 8);
#pragma unroll
            for (int m = 0; m < 4; m++)
#pragma unroll
                for (int n = 0; n < 4; n++)
                    acc[m][n] = mfma16(af[m], bfr[n], acc[m][n]);
        }
        __syncthreads();
        buf ^= 1;
    }
}

// ---------------- QKV projection GEMM -> plain bf16 C[4096][5120] ----------------
__global__ __launch_bounds__(256) void k_gemm_qkv(const ushort_t* __restrict__ Xb,
                                                  const ushort_t* __restrict__ Wt,
                                                  ushort_t* __restrict__ C) {
    __shared__ __align__(16) ushort_t ldsA[2 * 8192];
    __shared__ __align__(16) ushort_t ldsB[2 * 8192];
    f32x4 acc[4][4];
    int m0 = blockIdx.y * 128, n0 = blockIdx.x * 128;
    gemm_tile_db(Xb, Wt, m0, n0, ldsA, ldsB, acc);
    int t = threadIdx.x, w = t >> 6, l = t & 63;
    int wr = (w >> 1) * 64, wc = (w & 1) * 64, lo16 = l & 15, lg = l >> 4;
#pragma unroll
    for (int m = 0; m < 4; m++)
#pragma unroll
        for (int n = 0; n < 4; n++)
#pragma unroll
            for (int r = 0; r < 4; r++)
                C[(size_t)(m0 + wr + m * 16 + lg * 4 + r) * NC_ + (n0 + wc + n * 16 + lo16)] =
                    f2bf(acc[m][n][r]);
}

// ---------------- output GEMM: Yb @ Wo -> f32 ----------------
__global__ __launch_bounds__(256) void k_gemm_out(const ushort_t* __restrict__ Yb,
                                                  const ushort_t* __restrict__ Wot,
                                                  float* __restrict__ Out) {
    __shared__ __align__(16) ushort_t ldsA[2 * 8192];
    __shared__ __align__(16) ushort_t ldsB[2 * 8192];
    f32x4 acc[4][4];
    int m0 = blockIdx.y * 128, n0 = blockIdx.x * 128;
    gemm_tile_db(Yb, Wot, m0, n0, ldsA, ldsB, acc);
    int t = threadIdx.x, w = t >> 6, l = t & 63;
    int wr = (w >> 1) * 64, wc = (w & 1) * 64, lo16 = l & 15, lg = l >> 4;
#pragma unroll
    for (int m = 0; m < 4; m++)
#pragma unroll
        for (int n = 0; n < 4; n++)
#pragma unroll
            for (int r = 0; r < 4; r++)
                Out[(size_t)(m0 + wr + m * 16 + lg * 4 + r) * 1024 + (n0 + wc + n * 16 + lo16)] =
                    acc[m][n][r];
}

// ---------------- V transpose per head from C: [S][64] -> Vt[64][S] ----------------
__global__ __launch_bounds__(256) void k_transpose_v(const ushort_t* __restrict__ C,
                                                     ushort_t* __restrict__ Vt) {
    __shared__ ushort_t lds[64 * 72];
    int bh = blockIdx.x, s0 = blockIdx.y * 64;
    int b = bh >> 4, h = bh & 15;
    const ushort_t* src = C + (size_t)(b * S_ + s0) * NC_ + 4096 + h * 64;
    ushort_t* dst = Vt + (size_t)bh * HD_ * S_ + s0;
    int t = threadIdx.x;
#pragma unroll
    for (int i = 0; i < 16; i++) {
        int idx = i * 256 + t;
        int s = idx >> 6, d = idx & 63;
        lds[d * 72 + s] = src[(size_t)s * NC_ + d];
    }
    __syncthreads();
#pragma unroll
    for (int i = 0; i < 16; i++) {
        int idx = i * 256 + t;
        int d = idx >> 6, s = idx & 63;
        dst[(size_t)d * S_ + s] = lds[d * 72 + s];
    }
}

// ---------------- fused dual flash attention + memory term + stats ----------------
// R6-verified structure; ALiBi window W=28 log2-units. (Best-measured config.)
__global__ __launch_bounds__(256, 3) void k_attn(
    const ushort_t* __restrict__ Cg, const ushort_t* __restrict__ Vtg,
    const float* __restrict__ mask,
    const float* __restrict__ lam_q1, const float* __restrict__ lam_q2,
    const float* __restrict__ lam_k1, const float* __restrict__ lam_k2,
    const float* __restrict__ mgate, const float* __restrict__ memp,
    const float* __restrict__ zp, float* __restrict__ Oatt, float* __restrict__ stats) {
    __shared__ __align__(16) ushort_t smem[2 * 12288];
    __shared__ __align__(16) float ldsAdj[2][64];
    ushort_t* ldsM = smem;

    int bx = blockIdx.x;
    int xcd = bx & 7, slot = bx >> 3;
    int sub = slot & 3;
    int qt = 31 - (slot >> 2);
    int h = (sub & 1) ? (15 - xcd) : xcd;
    int b = sub >> 1;
    int bh = b * 16 + h;
    int q0 = qt * 64;
    int t = threadIdx.x, w = t >> 6, l = t & 63;
    int lo16 = l & 15, lg = l >> 4;

    const ushort_t* Cb  = Cg + (size_t)(b * S_) * NC_;
    const ushort_t* Qp  = Cb + h * 128;
    const ushort_t* Kp  = Cb + 2048 + h * 128;
    const ushort_t* Vt  = Vtg + (size_t)bh * HD_ * S_;

    int qrowA = q0 + w * 16 + lo16;
    us8 q1f[2], q2f[2];
    q1f[0] = *(const us8*)(Qp + (size_t)qrowA * NC_ + lg * 8);
    q1f[1] = *(const us8*)(Qp + (size_t)qrowA * NC_ + 32 + lg * 8);
    q2f[0] = *(const us8*)(Qp + (size_t)qrowA * NC_ + 64 + lg * 8);
    q2f[1] = *(const us8*)(Qp + (size_t)qrowA * NC_ + 96 + lg * 8);

    float la = 0.f, lb = 0.f;
    for (int i = 0; i < HD_; i++) { la += lam_q1[i] * lam_k1[i]; lb += lam_q2[i] * lam_k2[i]; }
    float lam = __expf(la) - __expf(lb) + 0.8f;

    const float LOG2E = 1.4426950408889634f;
    float slope2 = exp2f(-0.5f * (float)(h + 1)) * LOG2E;
    const float scale2 = 0.125f * LOG2E;

    int qcol = q0 + w * 16 + lo16;
    float qterm = -slope2 * (float)qcol - 8.0f;

    int koff[4];
#pragma unroll
    for (int n = 0; n < 4; n++) koff[n] = ((n >> 1) << 5) | (lg << 3) | ((n & 1) << 2);

    int fs = (int)floorf(((float)q0 - 63.0f - 28.0f / slope2) * (1.0f / 64.0f));
    if (fs < 0) fs = 0;

    int sx0 = (lg ^ (lo16 & 7)) * 8;
    int sx1 = ((4 + lg) ^ (lo16 & 7)) * 8;

    f32x4 o1[5], o2[5];
#pragma unroll
    for (int n = 0; n < 5; n++) { o1[n] = f32x4{0, 0, 0, 0}; o2[n] = f32x4{0, 0, 0, 0}; }

    const us8 ones8 = {0x3F80, 0x3F80, 0x3F80, 0x3F80, 0x3F80, 0x3F80, 0x3F80, 0x3F80};

    auto stage = [&](int buf, int kv0) {
        ushort_t* base = smem + buf * 12288;
#pragma unroll
        for (int i = 0; i < 2; i++) {
            int c = i * 256 + t, row = c >> 3;
            int co = ((c & 7) ^ (row & 7)) * 8;
            int kvsrc = kv0 + invpi(row);
            const ushort_t* krow = Kp + (size_t)kvsrc * NC_;
            gload16(krow + co, base + c * 8);
            gload16(krow + 64 + co, base + 4096 + c * 8);
            gload16(Vt + (size_t)row * S_ + kv0 + co, base + 8192 + c * 8);
        }
        if (t < 64) {
            int kvloc = invpi(t);
            ldsAdj[buf][t] = (1.f - mask[(size_t)b * S_ + kv0 + kvloc]) * -1.4426950e9f +
                             slope2 * (float)(kv0 + kvloc);
        }
    };

    auto score_pack = [&](const ushort_t* ldsK, const us8* qf, bool diag, int kv0,
                          const f32x4 (&madj)[4], us8 (&pa)[2]) {
        f32x4 s[4];
#pragma unroll
        for (int n = 0; n < 4; n++) s[n] = f32x4{0, 0, 0, 0};
        __builtin_amdgcn_s_setprio(1);
#pragma unroll
        for (int kk = 0; kk < 2; kk++) {
            int sxk = kk ? sx1 : sx0;
#pragma unroll
            for (int n = 0; n < 4; n++) {
                us8 kf = *(const us8*)(ldsK + (n * 16 + lo16) * 64 + sxk);
                s[n] = mfma16(kf, qf[kk], s[n]);
            }
        }
        __builtin_amdgcn_s_setprio(0);
#pragma unroll
        for (int n = 0; n < 4; n++)
#pragma unroll
            for (int r = 0; r < 4; r++)
                s[n][r] = fmaf(s[n][r], scale2, madj[n][r] + qterm);
        if (diag) {
#pragma unroll
            for (int n = 0; n < 4; n++) {
                int kvn = kv0 + koff[n];
#pragma unroll
                for (int r = 0; r < 4; r++)
                    if (kvn + r > qcol) s[n][r] = -1e30f;
            }
        }
        float p[4][4];
#pragma unroll
        for (int n = 0; n < 4; n++)
#pragma unroll
            for (int r = 0; r < 4; r++) p[n][r] = __builtin_amdgcn_exp2f(s[n][r]);
#pragma unroll
        for (int kk = 0; kk < 2; kk++) {
            u32x4 u;
            u[0] = cvt_pk_bf16(p[2 * kk][0], p[2 * kk][1]);
            u[1] = cvt_pk_bf16(p[2 * kk][2], p[2 * kk][3]);
            u[2] = cvt_pk_bf16(p[2 * kk + 1][0], p[2 * kk + 1][1]);
            u[3] = cvt_pk_bf16(p[2 * kk + 1][2], p[2 * kk + 1][3]);
            pa[kk] = __builtin_bit_cast(us8, u);
        }
    };

    int cur = 0;
    stage(0, qt * 64);
    __syncthreads();
    for (int step = qt; step >= fs; --step) {
        if (step - 1 >= fs) stage(cur ^ 1, (step - 1) * 64);
        int kv0 = step * 64;
        ushort_t* base = smem + cur * 12288;
        const ushort_t* ldsV = base + 8192;

        f32x4 madj[4];
#pragma unroll
        for (int n = 0; n < 4; n++)
            madj[n] = *(const f32x4*)(&ldsAdj[cur][n * 16 + lg * 4]);

        bool diag = (step == qt);
        us8 pa1[2], pa2[2];
        score_pack(base, q1f, diag, kv0, madj, pa1);
        score_pack(base + 4096, q2f, diag, kv0, madj, pa2);

        __builtin_amdgcn_s_setprio(1);
#pragma unroll
        for (int kk = 0; kk < 2; kk++) {
            o1[4] = mfma16(pa1[kk], ones8, o1[4]);
            o2[4] = mfma16(pa2[kk], ones8, o2[4]);
            int sxk = kk ? sx1 : sx0;
#pragma unroll
            for (int n = 0; n < 4; n++) {
                us8 vf = *(const us8*)(ldsV + (n * 16 + lo16) * 64 + sxk);
                o1[n] = mfma16(pa1[kk], vf, o1[n]);
                o2[n] = mfma16(pa2[kk], vf, o2[n]);
            }
        }
        __builtin_amdgcn_s_setprio(0);
        __syncthreads();
        cur ^= 1;
    }

    // ---- epilogue: sigma@mem, sigma@z, gate combine, stats ----
    for (int i = t; i < 80 * 64; i += 256) {
        int n = i >> 6, kd = i & 63;
        float v = 0.f;
        if (n < 64) v = memp[((size_t)h * 64 + kd) * 64 + n];
        else if (n == 64) v = zp[h * 64 + kd];
        ldsM[i] = f2bf(v);
    }
    __syncthreads();

    us8 sf[2];
#pragma unroll
    for (int kk = 0; kk < 2; kk++) {
#pragma unroll
        for (int j = 0; j < 8; j++) {
            float x = bf2f(q1f[kk][j]);
            float e = (x > 0.f) ? x : (__expf(x) - 1.f);
            sf[kk][j] = f2bf(e + 1.f);
        }
    }
    f32x4 mv[5];
#pragma unroll
    for (int n = 0; n < 5; n++) mv[n] = f32x4{0, 0, 0, 0};
#pragma unroll
    for (int kk = 0; kk < 2; kk++)
#pragma unroll
        for (int n = 0; n < 5; n++) {
            us8 mb = *(const us8*)(ldsM + (n * 16 + lo16) * 64 + kk * 32 + lg * 8);
            mv[n] = mfma16(sf[kk], mb, mv[n]);
        }
    float denom[4];
#pragma unroll
    for (int r = 0; r < 4; r++) denom[r] = __shfl(mv[4][r], lg * 16);

    float gsum = 0.f, gsq = 0.f;
#pragma unroll
    for (int n = 0; n < 4; n++) {
        int d = n * 16 + lo16;
        float gate = 1.f / (1.f + __expf(-mgate[h * HD_ + d]));
#pragma unroll
        for (int r = 0; r < 4; r++) {
            int q = q0 + w * 16 + lg * 4 + r;
            float dmv = mv[n][r] / denom[r];
            float oa = o1[n][r] / o1[4][r] - lam * (o2[n][r] / o2[4][r]);
            float val = gate * dmv + (1.f - gate) * oa;
            Oatt[((size_t)bh * S_ + q) * HD_ + d] = val;
            gsum += val;
            gsq += val * val;
        }
    }
#pragma unroll
    for (int off = 1; off < 64; off <<= 1) {
        gsum += __shfl_xor(gsum, off);
        gsq += __shfl_xor(gsq, off);
    }
    if (l == 0) {
        atomicAdd(&stats[bh * 2 + 0], gsum);
        atomicAdd(&stats[bh * 2 + 1], gsq);
    }
}

// ---------------- groupnorm normalize -> Yb bf16 [B][S][D] (x 0.2) ----------------
__global__ __launch_bounds__(256) void k_norm(const float* __restrict__ Oatt,
                                              const float* __restrict__ stats,
                                              const float* __restrict__ gw,
                                              const float* __restrict__ gb,
                                              ushort_t* __restrict__ Yb) {
    int i4 = (blockIdx.x * 256 + threadIdx.x) * 4;
    int bh = i4 >> 17;
    int rest = i4 & 131071;
    int s = rest >> 6, d = rest & 63;
    int b = bh >> 4, h = bh & 15;
    float mu = stats[bh * 2] * (1.f / 131072.f);
    float var = stats[bh * 2 + 1] * (1.f / 131072.f) - mu * mu;
    float rstd = rsqrtf(var + 1e-5f);
    float4 v = *reinterpret_cast<const float4*>(Oatt + i4);
    int c = h * 64 + d;
    ushort4 o;
    o.x = f2bf(((v.x - mu) * rstd * gw[c + 0] + gb[c + 0]) * 0.2f);
    o.y = f2bf(((v.y - mu) * rstd * gw[c + 1] + gb[c + 1]) * 0.2f);
    o.z = f2bf(((v.z - mu) * rstd * gw[c + 2] + gb[c + 2]) * 0.2f);
    o.w = f2bf(((v.w - mu) * rstd * gw[c + 3] + gb[c + 3]) * 0.2f);
    *reinterpret_cast<ushort4*>(Yb + ((size_t)(b * S_ + s)) * 1024 + c) = o;
}

extern "C" void kernel_launch(void* const* d_in, const int* in_sizes, int n_in,
                              void* d_out, int out_size, void* d_ws, size_t ws_size,
                              hipStream_t stream) {
    const float* X      = (const float*)d_in[0];
    const float* mask   = (const float*)d_in[1];
    const float* Wq     = (const float*)d_in[2];
    const float* Wk     = (const float*)d_in[3];
    const float* Wv     = (const float*)d_in[4];
    const float* Wo     = (const float*)d_in[5];
    const float* lam_q1 = (const float*)d_in[6];
    const float* lam_q2 = (const float*)d_in[7];
    const float* lam_k1 = (const float*)d_in[8];
    const float* lam_k2 = (const float*)d_in[9];
    const float* gw     = (const float*)d_in[10];
    const float* gb     = (const float*)d_in[11];
    const float* mgate  = (const float*)d_in[12];
    const float* memp   = (const float*)d_in[13];
    const float* zp     = (const float*)d_in[14];

    char* p = (char*)d_ws;
    auto alloc = [&](size_t bytes) -> char* {
        char* r = p;
        p += (bytes + 255) & ~(size_t)255;
        return r;
    };
    ushort_t* Xb  = (ushort_t*)alloc((size_t)4096 * 1024 * 2);
    ushort_t* Wt  = (ushort_t*)alloc((size_t)5120 * 1024 * 2);
    ushort_t* Wot = (ushort_t*)alloc((size_t)1024 * 1024 * 2);
    ushort_t* C   = (ushort_t*)alloc((size_t)4096 * NC_ * 2);
    ushort_t* Vt  = (ushort_t*)alloc((size_t)B_ * H_ * S_ * HD_ * 2);
    float*    Oat = (float*)alloc((size_t)B_ * H_ * S_ * HD_ * 4);
    ushort_t* Yb  = (ushort_t*)alloc((size_t)4096 * 1024 * 2);
    float*    st  = (float*)alloc(256);

    k_convert_x<<<4096, 256, 0, stream>>>(X, Xb);
    k_transpose_all<<<dim3(96, 16), 256, 0, stream>>>(Wq, Wk, Wv, Wo, Wt, Wot);
    k_gemm_qkv<<<dim3(40, 32), 256, 0, stream>>>(Xb, Wt, C);
    k_transpose_v<<<dim3(32, 32), 256, 0, stream>>>(C, Vt);
    hipMemsetAsync(st, 0, 64 * sizeof(float), stream);
    k_attn<<<1024, 256, 0, stream>>>(C, Vt, mask, lam_q1, lam_q2,
                                     lam_k1, lam_k2, mgate, memp, zp, Oat, st);
    k_norm<<<4096, 256, 0, stream>>>(Oat, st, gw, gb, Yb);
    k_gemm_out<<<dim3(8, 32), 256, 0, stream>>>(Yb, Wot, (float*)d_out);
}

// Round 17
// 178.070 us; speedup vs baseline: 1.3570x; 1.0149x over previous
//
#include <hip/hip_runtime.h>
#include <stdint.h>

#define B_ 2
#define S_ 2048
#define D_ 1024
#define H_ 16
#define HD_ 64
#define NC_ 5120   // QKV GEMM output width

typedef unsigned short ushort_t;
typedef __bf16 bf16x8_t __attribute__((ext_vector_type(8)));
typedef unsigned short us8 __attribute__((ext_vector_type(8)));
typedef float f32x4 __attribute__((ext_vector_type(4)));
typedef unsigned int u32x4 __attribute__((ext_vector_type(4)));

using gq_t = const unsigned int __attribute__((address_space(1)));
using lq_t = unsigned int __attribute__((address_space(3)));

__device__ __forceinline__ unsigned short f2bf(float f) {
    unsigned u = __builtin_bit_cast(unsigned, f);
    u += 0x7fffu + ((u >> 16) & 1u);
    return (unsigned short)(u >> 16);
}
__device__ __forceinline__ float bf2f(unsigned short h) {
    unsigned u = ((unsigned)h) << 16;
    return __builtin_bit_cast(float, u);
}
__device__ __forceinline__ unsigned cvt_pk_bf16(float lo, float hi) {
    unsigned r;
    asm("v_cvt_pk_bf16_f32 %0, %1, %2" : "=v"(r) : "v"(lo), "v"(hi));
    return r;
}
__device__ __forceinline__ f32x4 mfma16(us8 a, us8 b, f32x4 c) {
    return __builtin_amdgcn_mfma_f32_16x16x32_bf16(
        __builtin_bit_cast(bf16x8_t, a), __builtin_bit_cast(bf16x8_t, b), c, 0, 0, 0);
}
__device__ __forceinline__ void gload16(const void* g, void* l) {
    __builtin_amdgcn_global_load_lds((gq_t*)g, (lq_t*)l, 16, 0, 0);
}
// K-row storage bit-permutation: pos bits [kk|jh|g|r] <- kv bits [kk|g|jh|r]
__device__ __forceinline__ int invpi(int p) {
    return (p & 0x20) | ((p & 0x0C) << 1) | ((p & 0x10) >> 2) | (p & 3);
}

// ---------------- prep: X f32->bf16 convert + all weight transposes + st zero ----------------
// bx < 4096: convert X. bx >= 4096: weight transpose (decoded from the old (96,16) grid).
// Block 0 also zeroes the 64-float stats slab (runs before k_attn on-stream).
__global__ __launch_bounds__(256) void k_prep(const float* __restrict__ X,
                                              const float* __restrict__ Wq,
                                              const float* __restrict__ Wk,
                                              const float* __restrict__ Wv,
                                              const float* __restrict__ Wo,
                                              ushort_t* __restrict__ Xb,
                                              ushort_t* __restrict__ Wt,
                                              ushort_t* __restrict__ Wot,
                                              float* __restrict__ st) {
    __shared__ float lds[64 * 65];
    int bx = blockIdx.x;
    int t = threadIdx.x;
    if (bx < 4096) {
        if (bx == 0 && t < 64) st[t] = 0.f;
        int i = (bx * 256 + t) * 4;
        float4 v = *reinterpret_cast<const float4*>(X + i);
        ushort4 o;
        o.x = f2bf(v.x); o.y = f2bf(v.y); o.z = f2bf(v.z); o.w = f2bf(v.w);
        *reinterpret_cast<ushort4*>(Xb + i) = o;
        return;
    }
    int tb = bx - 4096;            // 0..1535
    int xb = tb % 96, yb = tb / 96;
    const float* W; ushort_t* dst; int N, nbase, x;
    if (xb < 32)      { W = Wq; dst = Wt;  N = 2048; nbase = 0;    x = xb; }
    else if (xb < 64) { W = Wk; dst = Wt;  N = 2048; nbase = 2048; x = xb - 32; }
    else if (xb < 80) { W = Wv; dst = Wt;  N = 1024; nbase = 4096; x = xb - 64; }
    else              { W = Wo; dst = Wot; N = 1024; nbase = 0;    x = xb - 80; }
    int n0 = x * 64, k0 = yb * 64;
#pragma unroll
    for (int i = 0; i < 16; i++) {
        int idx = i * 256 + t;
        int r = idx >> 6, c = idx & 63;
        lds[c * 65 + r] = W[(size_t)(k0 + r) * N + (n0 + c)];
    }
    __syncthreads();
#pragma unroll
    for (int i = 0; i < 16; i++) {
        int idx = i * 256 + t;
        int nn = idx >> 6, k = idx & 63;
        dst[(size_t)(nbase + n0 + nn) * 1024 + (k0 + k)] = f2bf(lds[nn * 65 + k]);
    }
}

// ------- 128x128x(K=1024) bf16 MFMA GEMM core, double-buffered prefetch -------
__device__ __forceinline__ void gemm_tile_db(const ushort_t* __restrict__ A,
                                             const ushort_t* __restrict__ Bt,
                                             int m0, int n0,
                                             ushort_t* ldsA, ushort_t* ldsB,  // each 2*8192
                                             f32x4 acc[4][4]) {
    const int K = 1024;
    int t = threadIdx.x;
    int w = t >> 6, l = t & 63;
    int wr = (w >> 1) * 64, wc = (w & 1) * 64;
    int lo16 = l & 15, lg = l >> 4;
#pragma unroll
    for (int m = 0; m < 4; m++)
#pragma unroll
        for (int n = 0; n < 4; n++) acc[m][n] = f32x4{0.f, 0.f, 0.f, 0.f};

    auto stage = [&](int buf, int k0) {
#pragma unroll
        for (int i = 0; i < 4; i++) {
            int c = i * 256 + t;
            int row = c >> 3, co = (c & 7) * 8;
            gload16(A + (size_t)(m0 + row) * K + k0 + co, ldsA + buf * 8192 + c * 8);
            gload16(Bt + (size_t)(n0 + row) * K + k0 + co, ldsB + buf * 8192 + c * 8);
        }
    };

    stage(0, 0);
    __syncthreads();
    int buf = 0;
    for (int k0 = 0; k0 < K; k0 += 64) {
        if (k0 + 64 < K) stage(buf ^ 1, k0 + 64);
        const ushort_t* la = ldsA + buf * 8192;
        const ushort_t* lb = ldsB + buf * 8192;
#pragma unroll
        for (int kk = 0; kk < 2; kk++) {
            us8 af[4], bfr[4];
#pragma unroll
            for (int m = 0; m < 4; m++)
                af[m] = *(const us8*)(la + (wr + m * 16 + lo16) * 64 + kk * 32 + lg * 8);
#pragma unroll
            for (int n = 0; n < 4; n++)
                bfr[n] = *(const us8*)(lb + (wc + n * 16 + lo16) * 64 + kk * 32 + lg * 8);
#pragma unroll
            for (int m = 0; m < 4; m++)
#pragma unroll
                for (int n = 0; n < 4; n++)
                    acc[m][n] = mfma16(af[m], bfr[n], acc[m][n]);
        }
        __syncthreads();
        buf ^= 1;
    }
}

// ---------------- QKV projection GEMM -> plain bf16 C[4096][5120] ----------------
__global__ __launch_bounds__(256) void k_gemm_qkv(const ushort_t* __restrict__ Xb,
                                                  const ushort_t* __restrict__ Wt,
                                                  ushort_t* __restrict__ C) {
    __shared__ __align__(16) ushort_t ldsA[2 * 8192];
    __shared__ __align__(16) ushort_t ldsB[2 * 8192];
    f32x4 acc[4][4];
    int m0 = blockIdx.y * 128, n0 = blockIdx.x * 128;
    gemm_tile_db(Xb, Wt, m0, n0, ldsA, ldsB, acc);
    int t = threadIdx.x, w = t >> 6, l = t & 63;
    int wr = (w >> 1) * 64, wc = (w & 1) * 64, lo16 = l & 15, lg = l >> 4;
#pragma unroll
    for (int m = 0; m < 4; m++)
#pragma unroll
        for (int n = 0; n < 4; n++)
#pragma unroll
            for (int r = 0; r < 4; r++)
                C[(size_t)(m0 + wr + m * 16 + lg * 4 + r) * NC_ + (n0 + wc + n * 16 + lo16)] =
                    f2bf(acc[m][n][r]);
}

// ---------------- output GEMM: Yb @ Wo -> f32 ----------------
__global__ __launch_bounds__(256) void k_gemm_out(const ushort_t* __restrict__ Yb,
                                                  const ushort_t* __restrict__ Wot,
                                                  float* __restrict__ Out) {
    __shared__ __align__(16) ushort_t ldsA[2 * 8192];
    __shared__ __align__(16) ushort_t ldsB[2 * 8192];
    f32x4 acc[4][4];
    int m0 = blockIdx.y * 128, n0 = blockIdx.x * 128;
    gemm_tile_db(Yb, Wot, m0, n0, ldsA, ldsB, acc);
    int t = threadIdx.x, w = t >> 6, l = t & 63;
    int wr = (w >> 1) * 64, wc = (w & 1) * 64, lo16 = l & 15, lg = l >> 4;
#pragma unroll
    for (int m = 0; m < 4; m++)
#pragma unroll
        for (int n = 0; n < 4; n++)
#pragma unroll
            for (int r = 0; r < 4; r++)
                Out[(size_t)(m0 + wr + m * 16 + lg * 4 + r) * 1024 + (n0 + wc + n * 16 + lo16)] =
                    acc[m][n][r];
}

// ---------------- V transpose per head from C: [S][64] -> Vt[64][S] ----------------
__global__ __launch_bounds__(256) void k_transpose_v(const ushort_t* __restrict__ C,
                                                     ushort_t* __restrict__ Vt) {
    __shared__ ushort_t lds[64 * 72];
    int bh = blockIdx.x, s0 = blockIdx.y * 64;
    int b = bh >> 4, h = bh & 15;
    const ushort_t* src = C + (size_t)(b * S_ + s0) * NC_ + 4096 + h * 64;
    ushort_t* dst = Vt + (size_t)bh * HD_ * S_ + s0;
    int t = threadIdx.x;
#pragma unroll
    for (int i = 0; i < 16; i++) {
        int idx = i * 256 + t;
        int s = idx >> 6, d = idx & 63;
        lds[d * 72 + s] = src[(size_t)s * NC_ + d];
    }
    __syncthreads();
#pragma unroll
    for (int i = 0; i < 16; i++) {
        int idx = i * 256 + t;
        int d = idx >> 6, s = idx & 63;
        dst[(size_t)d * S_ + s] = lds[d * 72 + s];
    }
}

// ---------------- fused dual flash attention + memory term + stats ----------------
// R6-verified structure; ALiBi window W=28 log2-units. (Best-measured config.)
__global__ __launch_bounds__(256, 3) void k_attn(
    const ushort_t* __restrict__ Cg, const ushort_t* __restrict__ Vtg,
    const float* __restrict__ mask,
    const float* __restrict__ lam_q1, const float* __restrict__ lam_q2,
    const float* __restrict__ lam_k1, const float* __restrict__ lam_k2,
    const float* __restrict__ mgate, const float* __restrict__ memp,
    const float* __restrict__ zp, float* __restrict__ Oatt, float* __restrict__ stats) {
    __shared__ __align__(16) ushort_t smem[2 * 12288];
    __shared__ __align__(16) float ldsAdj[2][64];
    ushort_t* ldsM = smem;

    int bx = blockIdx.x;
    int xcd = bx & 7, slot = bx >> 3;
    int sub = slot & 3;
    int qt = 31 - (slot >> 2);
    int h = (sub & 1) ? (15 - xcd) : xcd;
    int b = sub >> 1;
    int bh = b * 16 + h;
    int q0 = qt * 64;
    int t = threadIdx.x, w = t >> 6, l = t & 63;
    int lo16 = l & 15, lg = l >> 4;

    const ushort_t* Cb  = Cg + (size_t)(b * S_) * NC_;
    const ushort_t* Qp  = Cb + h * 128;
    const ushort_t* Kp  = Cb + 2048 + h * 128;
    const ushort_t* Vt  = Vtg + (size_t)bh * HD_ * S_;

    int qrowA = q0 + w * 16 + lo16;
    us8 q1f[2], q2f[2];
    q1f[0] = *(const us8*)(Qp + (size_t)qrowA * NC_ + lg * 8);
    q1f[1] = *(const us8*)(Qp + (size_t)qrowA * NC_ + 32 + lg * 8);
    q2f[0] = *(const us8*)(Qp + (size_t)qrowA * NC_ + 64 + lg * 8);
    q2f[1] = *(const us8*)(Qp + (size_t)qrowA * NC_ + 96 + lg * 8);

    float la = 0.f, lb = 0.f;
    for (int i = 0; i < HD_; i++) { la += lam_q1[i] * lam_k1[i]; lb += lam_q2[i] * lam_k2[i]; }
    float lam = __expf(la) - __expf(lb) + 0.8f;

    const float LOG2E = 1.4426950408889634f;
    float slope2 = exp2f(-0.5f * (float)(h + 1)) * LOG2E;
    const float scale2 = 0.125f * LOG2E;

    int qcol = q0 + w * 16 + lo16;
    float qterm = -slope2 * (float)qcol - 8.0f;

    int koff[4];
#pragma unroll
    for (int n = 0; n < 4; n++) koff[n] = ((n >> 1) << 5) | (lg << 3) | ((n & 1) << 2);

    int fs = (int)floorf(((float)q0 - 63.0f - 28.0f / slope2) * (1.0f / 64.0f));
    if (fs < 0) fs = 0;

    int sx0 = (lg ^ (lo16 & 7)) * 8;
    int sx1 = ((4 + lg) ^ (lo16 & 7)) * 8;

    f32x4 o1[5], o2[5];
#pragma unroll
    for (int n = 0; n < 5; n++) { o1[n] = f32x4{0, 0, 0, 0}; o2[n] = f32x4{0, 0, 0, 0}; }

    const us8 ones8 = {0x3F80, 0x3F80, 0x3F80, 0x3F80, 0x3F80, 0x3F80, 0x3F80, 0x3F80};

    auto stage = [&](int buf, int kv0) {
        ushort_t* base = smem + buf * 12288;
#pragma unroll
        for (int i = 0; i < 2; i++) {
            int c = i * 256 + t, row = c >> 3;
            int co = ((c & 7) ^ (row & 7)) * 8;
            int kvsrc = kv0 + invpi(row);
            const ushort_t* krow = Kp + (size_t)kvsrc * NC_;
            gload16(krow + co, base + c * 8);
            gload16(krow + 64 + co, base + 4096 + c * 8);
            gload16(Vt + (size_t)row * S_ + kv0 + co, base + 8192 + c * 8);
        }
        if (t < 64) {
            int kvloc = invpi(t);
            ldsAdj[buf][t] = (1.f - mask[(size_t)b * S_ + kv0 + kvloc]) * -1.4426950e9f +
                             slope2 * (float)(kv0 + kvloc);
        }
    };

    auto score_pack = [&](const ushort_t* ldsK, const us8* qf, bool diag, int kv0,
                          const f32x4 (&madj)[4], us8 (&pa)[2]) {
        f32x4 s[4];
#pragma unroll
        for (int n = 0; n < 4; n++) s[n] = f32x4{0, 0, 0, 0};
        __builtin_amdgcn_s_setprio(1);
#pragma unroll
        for (int kk = 0; kk < 2; kk++) {
            int sxk = kk ? sx1 : sx0;
#pragma unroll
            for (int n = 0; n < 4; n++) {
                us8 kf = *(const us8*)(ldsK + (n * 16 + lo16) * 64 + sxk);
                s[n] = mfma16(kf, qf[kk], s[n]);
            }
        }
        __builtin_amdgcn_s_setprio(0);
#pragma unroll
        for (int n = 0; n < 4; n++)
#pragma unroll
            for (int r = 0; r < 4; r++)
                s[n][r] = fmaf(s[n][r], scale2, madj[n][r] + qterm);
        if (diag) {
#pragma unroll
            for (int n = 0; n < 4; n++) {
                int kvn = kv0 + koff[n];
#pragma unroll
                for (int r = 0; r < 4; r++)
                    if (kvn + r > qcol) s[n][r] = -1e30f;
            }
        }
        float p[4][4];
#pragma unroll
        for (int n = 0; n < 4; n++)
#pragma unroll
            for (int r = 0; r < 4; r++) p[n][r] = __builtin_amdgcn_exp2f(s[n][r]);
#pragma unroll
        for (int kk = 0; kk < 2; kk++) {
            u32x4 u;
            u[0] = cvt_pk_bf16(p[2 * kk][0], p[2 * kk][1]);
            u[1] = cvt_pk_bf16(p[2 * kk][2], p[2 * kk][3]);
            u[2] = cvt_pk_bf16(p[2 * kk + 1][0], p[2 * kk + 1][1]);
            u[3] = cvt_pk_bf16(p[2 * kk + 1][2], p[2 * kk + 1][3]);
            pa[kk] = __builtin_bit_cast(us8, u);
        }
    };

    int cur = 0;
    stage(0, qt * 64);
    __syncthreads();
    for (int step = qt; step >= fs; --step) {
        if (step - 1 >= fs) stage(cur ^ 1, (step - 1) * 64);
        int kv0 = step * 64;
        ushort_t* base = smem + cur * 12288;
        const ushort_t* ldsV = base + 8192;

        f32x4 madj[4];
#pragma unroll
        for (int n = 0; n < 4; n++)
            madj[n] = *(const f32x4*)(&ldsAdj[cur][n * 16 + lg * 4]);

        bool diag = (step == qt);
        us8 pa1[2], pa2[2];
        score_pack(base, q1f, diag, kv0, madj, pa1);
        score_pack(base + 4096, q2f, diag, kv0, madj, pa2);

        __builtin_amdgcn_s_setprio(1);
#pragma unroll
        for (int kk = 0; kk < 2; kk++) {
            o1[4] = mfma16(pa1[kk], ones8, o1[4]);
            o2[4] = mfma16(pa2[kk], ones8, o2[4]);
            int sxk = kk ? sx1 : sx0;
#pragma unroll
            for (int n = 0; n < 4; n++) {
                us8 vf = *(const us8*)(ldsV + (n * 16 + lo16) * 64 + sxk);
                o1[n] = mfma16(pa1[kk], vf, o1[n]);
                o2[n] = mfma16(pa2[kk], vf, o2[n]);
            }
        }
        __builtin_amdgcn_s_setprio(0);
        __syncthreads();
        cur ^= 1;
    }

    // ---- epilogue: sigma@mem, sigma@z, gate combine, stats ----
    for (int i = t; i < 80 * 64; i += 256) {
        int n = i >> 6, kd = i & 63;
        float v = 0.f;
        if (n < 64) v = memp[((size_t)h * 64 + kd) * 64 + n];
        else if (n == 64) v = zp[h * 64 + kd];
        ldsM[i] = f2bf(v);
    }
    __syncthreads();

    us8 sf[2];
#pragma unroll
    for (int kk = 0; kk < 2; kk++) {
#pragma unroll
        for (int j = 0; j < 8; j++) {
            float x = bf2f(q1f[kk][j]);
            float e = (x > 0.f) ? x : (__expf(x) - 1.f);
            sf[kk][j] = f2bf(e + 1.f);
        }
    }
    f32x4 mv[5];
#pragma unroll
    for (int n = 0; n < 5; n++) mv[n] = f32x4{0, 0, 0, 0};
#pragma unroll
    for (int kk = 0; kk < 2; kk++)
#pragma unroll
        for (int n = 0; n < 5; n++) {
            us8 mb = *(const us8*)(ldsM + (n * 16 + lo16) * 64 + kk * 32 + lg * 8);
            mv[n] = mfma16(sf[kk], mb, mv[n]);
        }
    float denom[4];
#pragma unroll
    for (int r = 0; r < 4; r++) denom[r] = __shfl(mv[4][r], lg * 16);

    float gsum = 0.f, gsq = 0.f;
#pragma unroll
    for (int n = 0; n < 4; n++) {
        int d = n * 16 + lo16;
        float gate = 1.f / (1.f + __expf(-mgate[h * HD_ + d]));
#pragma unroll
        for (int r = 0; r < 4; r++) {
            int q = q0 + w * 16 + lg * 4 + r;
            float dmv = mv[n][r] / denom[r];
            float oa = o1[n][r] / o1[4][r] - lam * (o2[n][r] / o2[4][r]);
            float val = gate * dmv + (1.f - gate) * oa;
            Oatt[((size_t)bh * S_ + q) * HD_ + d] = val;
            gsum += val;
            gsq += val * val;
        }
    }
#pragma unroll
    for (int off = 1; off < 64; off <<= 1) {
        gsum += __shfl_xor(gsum, off);
        gsq += __shfl_xor(gsq, off);
    }
    if (l == 0) {
        atomicAdd(&stats[bh * 2 + 0], gsum);
        atomicAdd(&stats[bh * 2 + 1], gsq);
    }
}

// ---------------- groupnorm normalize -> Yb bf16 [B][S][D] (x 0.2) ----------------
__global__ __launch_bounds__(256) void k_norm(const float* __restrict__ Oatt,
                                              const float* __restrict__ stats,
                                              const float* __restrict__ gw,
                                              const float* __restrict__ gb,
                                              ushort_t* __restrict__ Yb) {
    int i4 = (blockIdx.x * 256 + threadIdx.x) * 4;
    int bh = i4 >> 17;
    int rest = i4 & 131071;
    int s = rest >> 6, d = rest & 63;
    int b = bh >> 4, h = bh & 15;
    float mu = stats[bh * 2] * (1.f / 131072.f);
    float var = stats[bh * 2 + 1] * (1.f / 131072.f) - mu * mu;
    float rstd = rsqrtf(var + 1e-5f);
    float4 v = *reinterpret_cast<const float4*>(Oatt + i4);
    int c = h * 64 + d;
    ushort4 o;
    o.x = f2bf(((v.x - mu) * rstd * gw[c + 0] + gb[c + 0]) * 0.2f);
    o.y = f2bf(((v.y - mu) * rstd * gw[c + 1] + gb[c + 1]) * 0.2f);
    o.z = f2bf(((v.z - mu) * rstd * gw[c + 2] + gb[c + 2]) * 0.2f);
    o.w = f2bf(((v.w - mu) * rstd * gw[c + 3] + gb[c + 3]) * 0.2f);
    *reinterpret_cast<ushort4*>(Yb + ((size_t)(b * S_ + s)) * 1024 + c) = o;
}

extern "C" void kernel_launch(void* const* d_in, const int* in_sizes, int n_in,
                              void* d_out, int out_size, void* d_ws, size_t ws_size,
                              hipStream_t stream) {
    const float* X      = (const float*)d_in[0];
    const float* mask   = (const float*)d_in[1];
    const float* Wq     = (const float*)d_in[2];
    const float* Wk     = (const float*)d_in[3];
    const float* Wv     = (const float*)d_in[4];
    const float* Wo     = (const float*)d_in[5];
    const float* lam_q1 = (const float*)d_in[6];
    const float* lam_q2 = (const float*)d_in[7];
    const float* lam_k1 = (const float*)d_in[8];
    const float* lam_k2 = (const float*)d_in[9];
    const float* gw     = (const float*)d_in[10];
    const float* gb     = (const float*)d_in[11];
    const float* mgate  = (const float*)d_in[12];
    const float* memp   = (const float*)d_in[13];
    const float* zp     = (const float*)d_in[14];

    char* p = (char*)d_ws;
    auto alloc = [&](size_t bytes) -> char* {
        char* r = p;
        p += (bytes + 255) & ~(size_t)255;
        return r;
    };
    ushort_t* Xb  = (ushort_t*)alloc((size_t)4096 * 1024 * 2);
    ushort_t* Wt  = (ushort_t*)alloc((size_t)5120 * 1024 * 2);
    ushort_t* Wot = (ushort_t*)alloc((size_t)1024 * 1024 * 2);
    ushort_t* C   = (ushort_t*)alloc((size_t)4096 * NC_ * 2);
    ushort_t* Vt  = (ushort_t*)alloc((size_t)B_ * H_ * S_ * HD_ * 2);
    float*    Oat = (float*)alloc((size_t)B_ * H_ * S_ * HD_ * 4);
    ushort_t* Yb  = (ushort_t*)alloc((size_t)4096 * 1024 * 2);
    float*    st  = (float*)alloc(256);

    k_prep<<<5632, 256, 0, stream>>>(X, Wq, Wk, Wv, Wo, Xb, Wt, Wot, st);
    k_gemm_qkv<<<dim3(40, 32), 256, 0, stream>>>(Xb, Wt, C);
    k_transpose_v<<<dim3(32, 32), 256, 0, stream>>>(C, Vt);
    k_attn<<<1024, 256, 0, stream>>>(C, Vt, mask, lam_q1, lam_q2,
                                     lam_k1, lam_k2, mgate, memp, zp, Oat, st);
    k_norm<<<4096, 256, 0, stream>>>(Oat, st, gw, gb, Yb);
    k_gemm_out<<<dim3(8, 32), 256, 0, stream>>>(Yb, Wot, (float*)d_out);
}